// Round 4
// baseline (567.549 us; speedup 1.0000x reference)
//
#include <hip/hip_runtime.h>
#include <hip/hip_bf16.h>

#define B_ROWS  2048
#define T_DIM   8
#define IN_DIM  1024
#define OUT_DIM 4096
#define NE      12

#define M_TILE 128
#define N_TILE 128
#define K_STEP 32
#define NSTEP  (IN_DIM / K_STEP)

typedef __attribute__((ext_vector_type(8))) short short8;
typedef __attribute__((ext_vector_type(4))) float f32x4;

union S8U { short8 s; unsigned u[4]; };

// two floats -> packed bf16x2 (v_cvt_pk_bf16_f32, RNE)
__device__ __forceinline__ unsigned cvt2(float a, float b) {
  __hip_bfloat162 h = __float22bfloat162_rn(make_float2(a, b));
  union { __hip_bfloat162 h; unsigned u; } c; c.h = h;
  return c.u;
}

// slot swizzle: injects s[3],s[6],s[4] into s[0],s[1],s[2].
// Verified: W-writes, X-writes, and fragment reads all map 64 lanes
// uniformly over the 8 LDS bank-groups (conflict-free-equivalent).
__device__ __forceinline__ int swz(int s) {
  return s ^ ((s >> 3) & 1) ^ (((s >> 6) & 1) << 1) ^ (((s >> 4) & 1) << 2);
}

// ---------------- kernel P: transpose Wg[4096][12] -> WgT[12][4096] --------
__global__ __launch_bounds__(256) void wg_transpose(
    const float* __restrict__ Wg, float* __restrict__ wgt)
{
  const int c = blockIdx.x * 256 + threadIdx.x;   // 0..4095
  #pragma unroll
  for (int e = 0; e < NE; ++e)
    wgt[(size_t)e * OUT_DIM + c] = Wg[(size_t)c * NE + e];
}

// ---------------- kernel A: gate logits -> top1 -> per-expert row buckets --
// Same per-thread column ownership and per-e accumulation order as the
// passing round-3 version; Wg reads now coalesced via WgT.
__global__ __launch_bounds__(256) void gate_kernel(
    const float* __restrict__ t, const float* __restrict__ wgt,
    const float* __restrict__ bg, int* __restrict__ counts,
    int* __restrict__ rowlist)
{
  const int b   = blockIdx.x;
  const int tid = threadIdx.x;
  const float* tb = t + (size_t)b * T_DIM * OUT_DIM;

  float4 m[4];
  #pragma unroll
  for (int it = 0; it < 4; ++it) {
    const int c = (tid + it * 256) * 4;
    float4 s = make_float4(0.f, 0.f, 0.f, 0.f);
    #pragma unroll
    for (int tt = 0; tt < T_DIM; ++tt) {
      const float4 v = *(const float4*)(tb + (size_t)tt * OUT_DIM + c);
      s.x += v.x; s.y += v.y; s.z += v.z; s.w += v.w;
    }
    m[it] = make_float4(s.x * 0.125f, s.y * 0.125f, s.z * 0.125f, s.w * 0.125f);
  }

  float part[NE];
  #pragma unroll
  for (int e = 0; e < NE; ++e) {
    float acc = 0.f;
    #pragma unroll
    for (int it = 0; it < 4; ++it) {
      const int c = (tid + it * 256) * 4;
      const float4 w = *(const float4*)(wgt + (size_t)e * OUT_DIM + c);
      acc += m[it].x * w.x; acc += m[it].y * w.y;
      acc += m[it].z * w.z; acc += m[it].w * w.w;
    }
    part[e] = acc;
  }

  double d[NE];
  #pragma unroll
  for (int e = 0; e < NE; ++e) d[e] = (double)part[e];
  #pragma unroll
  for (int off = 32; off > 0; off >>= 1) {
    #pragma unroll
    for (int e = 0; e < NE; ++e) d[e] += __shfl_down(d[e], off, 64);
  }

  __shared__ double wsred[4][NE];
  const int lane = tid & 63, wave = tid >> 6;
  if (lane == 0) {
    #pragma unroll
    for (int e = 0; e < NE; ++e) wsred[wave][e] = d[e];
  }
  __syncthreads();

  if (tid == 0) {
    double best = -1e300; int bi = 0;
    #pragma unroll
    for (int e = 0; e < NE; ++e) {
      const double v = wsred[0][e] + wsred[1][e] + wsred[2][e] + wsred[3][e] + (double)bg[e];
      if (v > best) { best = v; bi = e; }
    }
    const int pos = atomicAdd(&counts[bi], 1);
    rowlist[bi * B_ROWS + pos] = b;
  }
}

// fallback gate (round-3 version) if workspace can't hold WgT
__global__ __launch_bounds__(256) void gate_fallback(
    const float* __restrict__ t, const float* __restrict__ Wg,
    const float* __restrict__ bg, int* __restrict__ counts,
    int* __restrict__ rowlist)
{
  const int b   = blockIdx.x;
  const int tid = threadIdx.x;
  const float* tb = t + (size_t)b * T_DIM * OUT_DIM;

  float part[NE];
  #pragma unroll
  for (int e = 0; e < NE; ++e) part[e] = 0.f;
  #pragma unroll
  for (int it = 0; it < 4; ++it) {
    const int c = (tid + it * 256) * 4;
    float4 s = make_float4(0.f, 0.f, 0.f, 0.f);
    #pragma unroll
    for (int tt = 0; tt < T_DIM; ++tt) {
      const float4 v = *(const float4*)(tb + (size_t)tt * OUT_DIM + c);
      s.x += v.x; s.y += v.y; s.z += v.z; s.w += v.w;
    }
    const float mm[4] = { s.x * 0.125f, s.y * 0.125f, s.z * 0.125f, s.w * 0.125f };
    #pragma unroll
    for (int j = 0; j < 4; ++j) {
      const float* wg = Wg + (size_t)(c + j) * NE;
      #pragma unroll
      for (int e = 0; e < NE; ++e) part[e] += mm[j] * wg[e];
    }
  }
  double d[NE];
  #pragma unroll
  for (int e = 0; e < NE; ++e) d[e] = (double)part[e];
  #pragma unroll
  for (int off = 32; off > 0; off >>= 1) {
    #pragma unroll
    for (int e = 0; e < NE; ++e) d[e] += __shfl_down(d[e], off, 64);
  }
  __shared__ double wsred[4][NE];
  const int lane = tid & 63, wave = tid >> 6;
  if (lane == 0) {
    #pragma unroll
    for (int e = 0; e < NE; ++e) wsred[wave][e] = d[e];
  }
  __syncthreads();
  if (tid == 0) {
    double best = -1e300; int bi = 0;
    #pragma unroll
    for (int e = 0; e < NE; ++e) {
      const double v = wsred[0][e] + wsred[1][e] + wsred[2][e] + wsred[3][e] + (double)bg[e];
      if (v > best) { best = v; bi = e; }
    }
    const int pos = atomicAdd(&counts[bi], 1);
    rowlist[bi * B_ROWS + pos] = b;
  }
}

// ---------------- kernel B: grouped bf16-MFMA GEMM --------------------------
// Role-split staging: waves 0-1 stage W (coalesced float4 along OUT_DIM +
// register transpose), waves 2-3 stage x. Fragment-order LDS with XOR slot
// swizzle; all LDS traffic conflict-free-equivalent. Double-buffered, one
// barrier per K-step.
__global__ __launch_bounds__(256) void expert_gemm(
    const float* __restrict__ x, const float* __restrict__ W,
    const float* __restrict__ bias, const int* __restrict__ counts,
    const int* __restrict__ rowlist, float* __restrict__ out)
{
  const int e    = blockIdx.z;
  const int cnt  = counts[e];
  const int row0 = blockIdx.y * M_TILE;
  if (row0 >= cnt) return;
  const int c0   = blockIdx.x * N_TILE;
  const int* rl  = rowlist + e * B_ROWS;

  __shared__ short8 xa[2][512];    // A tile, fragment slots (swizzled)
  __shared__ short8 wbuf[2][512];  // B tile, fragment slots (swizzled)

  const int tid  = threadIdx.x;
  const int lane = tid & 63;
  const int wave = tid >> 6;
  const bool isW = (tid < 128);

  // ---- staging geometry ----
  // W role (tid 0..127): g = (tid>>5)&3, cols 4*(tid&31)..+3, k = 8g+j
  // X role (u = tid-128): g = u&3, rows (u>>2)*4 .. +3
  const int wgk = (tid >> 5) & 3;
  const int wcg = tid & 31;
  const float* wbase = W + (size_t)e * IN_DIM * OUT_DIM
                         + (size_t)(8 * wgk) * OUT_DIM + c0 + 4 * wcg;

  const int u   = tid - 128;
  const int xg  = u & 3;
  const int xr0 = (u >> 2) * 4;
  const float* xp[4];
  int dst[4];
  if (isW) {
    #pragma unroll
    for (int c = 0; c < 4; ++c) {
      const int col = 4 * wcg + c;
      dst[c] = swz((col >> 4) * 64 + wgk * 16 + (col & 15));
    }
  } else {
    #pragma unroll
    for (int jr = 0; jr < 4; ++jr) {
      const int r = xr0 + jr;
      const int g = row0 + r;
      xp[jr] = x + (size_t)rl[g < cnt ? g : cnt - 1] * IN_DIM + 8 * xg;
      dst[jr] = swz((r >> 4) * 64 + xg * 16 + (r & 15));
    }
  }

  // ---- MFMA geometry ----
  const int wm = (wave >> 1) * 64;
  const int wn = (wave & 1) * 64;
  const int abase = (wave >> 1) * 256;
  const int bbase = (wave & 1) * 256;
  const int lb = ((lane >> 3) & 1) | (((lane >> 4) & 1) << 2);  // read-side swizzle bits

  f32x4 acc[4][4];
  #pragma unroll
  for (int m = 0; m < 4; ++m)
    #pragma unroll
    for (int n = 0; n < 4; ++n)
      #pragma unroll
      for (int q = 0; q < 4; ++q) acc[m][n][q] = 0.f;

  float st[32];

#define STAGE_LOADS(K)                                                    \
  if (isW) {                                                              \
    _Pragma("unroll")                                                     \
    for (int j = 0; j < 8; ++j) {                                         \
      const float4 v = *(const float4*)(wbase + (size_t)((K) + j) * OUT_DIM); \
      st[j * 4 + 0] = v.x; st[j * 4 + 1] = v.y;                           \
      st[j * 4 + 2] = v.z; st[j * 4 + 3] = v.w;                           \
    }                                                                     \
  } else {                                                                \
    _Pragma("unroll")                                                     \
    for (int jr = 0; jr < 4; ++jr) {                                      \
      const float4 v0 = *(const float4*)(xp[jr] + (K));                   \
      const float4 v1 = *(const float4*)(xp[jr] + (K) + 4);               \
      st[jr * 8 + 0] = v0.x; st[jr * 8 + 1] = v0.y;                       \
      st[jr * 8 + 2] = v0.z; st[jr * 8 + 3] = v0.w;                       \
      st[jr * 8 + 4] = v1.x; st[jr * 8 + 5] = v1.y;                       \
      st[jr * 8 + 6] = v1.z; st[jr * 8 + 7] = v1.w;                       \
    }                                                                     \
  }

  STAGE_LOADS(0);

  for (int it = 0; it < NSTEP; ++it) {
    // convert staged registers -> bf16 fragment slots
    S8U o[4];
    if (isW) {
      #pragma unroll
      for (int c = 0; c < 4; ++c)
        #pragma unroll
        for (int q = 0; q < 4; ++q)
          o[c].u[q] = cvt2(st[(2 * q) * 4 + c], st[(2 * q + 1) * 4 + c]);
    } else {
      #pragma unroll
      for (int jr = 0; jr < 4; ++jr)
        #pragma unroll
        for (int q = 0; q < 4; ++q)
          o[jr].u[q] = cvt2(st[jr * 8 + 2 * q], st[jr * 8 + 2 * q + 1]);
    }

    if (it + 1 < NSTEP) STAGE_LOADS((it + 1) * K_STEP);

    const int buf = it & 1;
    if (isW) {
      #pragma unroll
      for (int c = 0; c < 4; ++c) wbuf[buf][dst[c]] = o[c].s;
    } else {
      #pragma unroll
      for (int jr = 0; jr < 4; ++jr) xa[buf][dst[jr]] = o[jr].s;
    }
    __syncthreads();

    short8 af[4], bf[4];
    #pragma unroll
    for (int m = 0; m < 4; ++m)
      af[m] = xa[buf][((abase + m * 64 + lane) ^ lb) ^ ((m & 1) << 1)];
    #pragma unroll
    for (int n = 0; n < 4; ++n)
      bf[n] = wbuf[buf][((bbase + n * 64 + lane) ^ lb) ^ ((n & 1) << 1)];
    #pragma unroll
    for (int m = 0; m < 4; ++m)
      #pragma unroll
      for (int n = 0; n < 4; ++n)
        acc[m][n] = __builtin_amdgcn_mfma_f32_16x16x32_bf16(af[m], bf[n], acc[m][n], 0, 0, 0);
  }
#undef STAGE_LOADS

  // ---- epilogue: C/D layout col = lane&15, row = (lane>>4)*4 + r ----
  const int lr = lane & 15;
  const int lq = (lane >> 4) * 4;
  float bcol[4];
  #pragma unroll
  for (int n = 0; n < 4; ++n)
    bcol[n] = bias[e * OUT_DIM + c0 + wn + n * 16 + lr];

  #pragma unroll
  for (int m = 0; m < 4; ++m) {
    #pragma unroll
    for (int r = 0; r < 4; ++r) {
      const int gidx = row0 + wm + m * 16 + lq + r;
      if (gidx >= cnt) continue;
      const int grow = rl[gidx];
      float* orow = out + (size_t)grow * OUT_DIM;
      #pragma unroll
      for (int n = 0; n < 4; ++n) {
        const int col = c0 + wn + n * 16 + lr;
        orow[col] = acc[m][n][r] + bcol[n];
      }
    }
  }
}

extern "C" void kernel_launch(void* const* d_in, const int* in_sizes, int n_in,
                              void* d_out, int out_size, void* d_ws, size_t ws_size,
                              hipStream_t stream) {
  (void)in_sizes; (void)n_in; (void)out_size;
  const float* x  = (const float*)d_in[0];
  const float* t  = (const float*)d_in[1];
  const float* W  = (const float*)d_in[2];
  const float* bb = (const float*)d_in[3];
  const float* Wg = (const float*)d_in[4];
  const float* bg = (const float*)d_in[5];
  float* out = (float*)d_out;

  int*   counts  = (int*)d_ws;                                  // 16 ints
  int*   rowlist = (int*)d_ws + 16;                             // 12*2048 ints
  float* wgt     = (float*)((char*)d_ws + 64 + NE * B_ROWS * 4);// 12*4096 f32
  const size_t need = 64 + (size_t)NE * B_ROWS * 4 + (size_t)NE * OUT_DIM * 4;

  hipMemsetAsync(counts, 0, 16 * sizeof(int), stream);
  if (ws_size >= need) {
    wg_transpose<<<OUT_DIM / 256, 256, 0, stream>>>(Wg, wgt);
    gate_kernel<<<B_ROWS, 256, 0, stream>>>(t, wgt, bg, counts, rowlist);
  } else {
    gate_fallback<<<B_ROWS, 256, 0, stream>>>(t, Wg, bg, counts, rowlist);
  }

  dim3 grid(OUT_DIM / N_TILE, (B_ROWS + M_TILE - 1) / M_TILE, NE);
  expert_gemm<<<grid, 256, 0, stream>>>(x, W, bb, counts, rowlist, out);
}

// Round 5
// 172.231 us; speedup vs baseline: 3.2953x; 3.2953x over previous
//
#include <hip/hip_runtime.h>
#include <hip/hip_bf16.h>

#define B_ROWS  2048
#define T_DIM   8
#define IN_DIM  1024
#define OUT_DIM 4096
#define NE      12

#define M_TILE 128
#define N_TILE 128
#define K_STEP 32
#define NSTEP  (IN_DIM / K_STEP)

typedef __attribute__((ext_vector_type(8))) short short8;
typedef __attribute__((ext_vector_type(4))) float f32x4;

union S8U { short8 s; unsigned u[4]; };

// two floats -> packed bf16x2 (v_cvt_pk_bf16_f32, RNE)
__device__ __forceinline__ unsigned cvt2(float a, float b) {
  __hip_bfloat162 h = __float22bfloat162_rn(make_float2(a, b));
  union { __hip_bfloat162 h; unsigned u; } c; c.h = h;
  return c.u;
}

// barrier WITHOUT vmcnt drain: ds-write visibility only (lgkmcnt), so
// prefetched global loads stay in flight across the barrier (T4 pattern).
__device__ __forceinline__ void barrier_lgkm() {
  asm volatile("s_waitcnt lgkmcnt(0)" ::: "memory");
  __builtin_amdgcn_s_barrier();
}

// ---------------- kernel P: transpose Wg[4096][12] -> WgT[12][4096] --------
__global__ __launch_bounds__(256) void wg_transpose(
    const float* __restrict__ Wg, float* __restrict__ wgt)
{
  const int c = blockIdx.x * 256 + threadIdx.x;   // 0..4095
  #pragma unroll
  for (int e = 0; e < NE; ++e)
    wgt[(size_t)e * OUT_DIM + c] = Wg[(size_t)c * NE + e];
}

// ---------------- kernel A: gate (round-4 passing version, unchanged) ------
__global__ __launch_bounds__(256) void gate_kernel(
    const float* __restrict__ t, const float* __restrict__ wgt,
    const float* __restrict__ bg, int* __restrict__ counts,
    int* __restrict__ rowlist)
{
  const int b   = blockIdx.x;
  const int tid = threadIdx.x;
  const float* tb = t + (size_t)b * T_DIM * OUT_DIM;

  float4 m[4];
  #pragma unroll
  for (int it = 0; it < 4; ++it) {
    const int c = (tid + it * 256) * 4;
    float4 s = make_float4(0.f, 0.f, 0.f, 0.f);
    #pragma unroll
    for (int tt = 0; tt < T_DIM; ++tt) {
      const float4 v = *(const float4*)(tb + (size_t)tt * OUT_DIM + c);
      s.x += v.x; s.y += v.y; s.z += v.z; s.w += v.w;
    }
    m[it] = make_float4(s.x * 0.125f, s.y * 0.125f, s.z * 0.125f, s.w * 0.125f);
  }

  float part[NE];
  #pragma unroll
  for (int e = 0; e < NE; ++e) {
    float acc = 0.f;
    #pragma unroll
    for (int it = 0; it < 4; ++it) {
      const int c = (tid + it * 256) * 4;
      const float4 w = *(const float4*)(wgt + (size_t)e * OUT_DIM + c);
      acc += m[it].x * w.x; acc += m[it].y * w.y;
      acc += m[it].z * w.z; acc += m[it].w * w.w;
    }
    part[e] = acc;
  }

  double d[NE];
  #pragma unroll
  for (int e = 0; e < NE; ++e) d[e] = (double)part[e];
  #pragma unroll
  for (int off = 32; off > 0; off >>= 1) {
    #pragma unroll
    for (int e = 0; e < NE; ++e) d[e] += __shfl_down(d[e], off, 64);
  }

  __shared__ double wsred[4][NE];
  const int lane = tid & 63, wave = tid >> 6;
  if (lane == 0) {
    #pragma unroll
    for (int e = 0; e < NE; ++e) wsred[wave][e] = d[e];
  }
  __syncthreads();

  if (tid == 0) {
    double best = -1e300; int bi = 0;
    #pragma unroll
    for (int e = 0; e < NE; ++e) {
      const double v = wsred[0][e] + wsred[1][e] + wsred[2][e] + wsred[3][e] + (double)bg[e];
      if (v > best) { best = v; bi = e; }
    }
    const int pos = atomicAdd(&counts[bi], 1);
    rowlist[bi * B_ROWS + pos] = b;
  }
}

// fallback gate if workspace can't hold WgT
__global__ __launch_bounds__(256) void gate_fallback(
    const float* __restrict__ t, const float* __restrict__ Wg,
    const float* __restrict__ bg, int* __restrict__ counts,
    int* __restrict__ rowlist)
{
  const int b   = blockIdx.x;
  const int tid = threadIdx.x;
  const float* tb = t + (size_t)b * T_DIM * OUT_DIM;

  float part[NE];
  #pragma unroll
  for (int e = 0; e < NE; ++e) part[e] = 0.f;
  #pragma unroll
  for (int it = 0; it < 4; ++it) {
    const int c = (tid + it * 256) * 4;
    float4 s = make_float4(0.f, 0.f, 0.f, 0.f);
    #pragma unroll
    for (int tt = 0; tt < T_DIM; ++tt) {
      const float4 v = *(const float4*)(tb + (size_t)tt * OUT_DIM + c);
      s.x += v.x; s.y += v.y; s.z += v.z; s.w += v.w;
    }
    const float mm[4] = { s.x * 0.125f, s.y * 0.125f, s.z * 0.125f, s.w * 0.125f };
    #pragma unroll
    for (int j = 0; j < 4; ++j) {
      const float* wg = Wg + (size_t)(c + j) * NE;
      #pragma unroll
      for (int e = 0; e < NE; ++e) part[e] += mm[j] * wg[e];
    }
  }
  double d[NE];
  #pragma unroll
  for (int e = 0; e < NE; ++e) d[e] = (double)part[e];
  #pragma unroll
  for (int off = 32; off > 0; off >>= 1) {
    #pragma unroll
    for (int e = 0; e < NE; ++e) d[e] += __shfl_down(d[e], off, 64);
  }
  __shared__ double wsred[4][NE];
  const int lane = tid & 63, wave = tid >> 6;
  if (lane == 0) {
    #pragma unroll
    for (int e = 0; e < NE; ++e) wsred[wave][e] = d[e];
  }
  __syncthreads();
  if (tid == 0) {
    double best = -1e300; int bi = 0;
    #pragma unroll
    for (int e = 0; e < NE; ++e) {
      const double v = wsred[0][e] + wsred[1][e] + wsred[2][e] + wsred[3][e] + (double)bg[e];
      if (v > best) { best = v; bi = e; }
    }
    const int pos = atomicAdd(&counts[bi], 1);
    rowlist[bi * B_ROWS + pos] = b;
  }
}

// ---------------- kernel B: grouped bf16-MFMA GEMM (round-3 structure, -----
// fragment-order LDS slots, double-buffered, reg prefetch) with the ONLY
// change: raw barrier that does NOT drain vmcnt, so next-step global loads
// remain in flight across the barrier and HBM latency hides under MFMA.
__global__ __launch_bounds__(256) void expert_gemm(
    const float* __restrict__ x, const float* __restrict__ W,
    const float* __restrict__ bias, const int* __restrict__ counts,
    const int* __restrict__ rowlist, float* __restrict__ out)
{
  const int e    = blockIdx.z;
  const int cnt  = counts[e];
  const int row0 = blockIdx.y * M_TILE;
  if (row0 >= cnt) return;
  const int c0   = blockIdx.x * N_TILE;
  const int* rl  = rowlist + e * B_ROWS;

  __shared__ short8 xa[2][512];   // 2 x 8 KiB
  __shared__ short8 wb[2][512];   // 2 x 8 KiB

  const int tid  = threadIdx.x;
  const int lane = tid & 63;
  const int wave = tid >> 6;

  // staging geometry: thread owns slots {tid, tid+256} on both sides
  const int sg  = (tid >> 4) & 3;   // k-subgroup
  const int slr = tid & 15;         // lr / lc
  const int smb = tid >> 6;         // frag-block for slot tid (slot tid+256: +4)

  int arow0, arow1;
  {
    const int g0 = row0 + smb * 16 + slr;
    const int g1 = row0 + (smb + 4) * 16 + slr;
    arow0 = rl[g0 < cnt ? g0 : cnt - 1];
    arow1 = rl[g1 < cnt ? g1 : cnt - 1];
  }
  const float* xp0 = x + (size_t)arow0 * IN_DIM + sg * 8;
  const float* xp1 = x + (size_t)arow1 * IN_DIM + sg * 8;
  const float* wp  = W + (size_t)e * IN_DIM * OUT_DIM
                       + (size_t)(sg * 8) * OUT_DIM + c0 + smb * 16 + slr;

  // MFMA geometry
  const int wm = (wave >> 1) * 64;
  const int wn = (wave & 1) * 64;
  const int abase = (wave >> 1) * 256;
  const int bbase = (wave & 1) * 256;

  f32x4 acc[4][4];
  #pragma unroll
  for (int m = 0; m < 4; ++m)
    #pragma unroll
    for (int n = 0; n < 4; ++n)
      #pragma unroll
      for (int q = 0; q < 4; ++q) acc[m][n][q] = 0.f;

  // staging registers
  float4 a0lo, a0hi, a1lo, a1hi;
  float w0[8], w1[8];

#define ISSUE_LOADS(K)                                                  \
  {                                                                     \
    a0lo = *(const float4*)(xp0 + (K));                                 \
    a0hi = *(const float4*)(xp0 + (K) + 4);                             \
    a1lo = *(const float4*)(xp1 + (K));                                 \
    a1hi = *(const float4*)(xp1 + (K) + 4);                             \
    const float* p = wp + (size_t)(K) * OUT_DIM;                        \
    _Pragma("unroll")                                                   \
    for (int j = 0; j < 8; ++j) {                                       \
      w0[j] = p[(size_t)j * OUT_DIM];                                   \
      w1[j] = p[(size_t)j * OUT_DIM + 64];                              \
    }                                                                   \
  }

  ISSUE_LOADS(0);

  for (int it = 0; it < NSTEP; ++it) {
    // convert staged registers -> bf16 (dep-waits on loads)
    S8U av0, av1, bv0, bv1;
    av0.u[0] = cvt2(a0lo.x, a0lo.y); av0.u[1] = cvt2(a0lo.z, a0lo.w);
    av0.u[2] = cvt2(a0hi.x, a0hi.y); av0.u[3] = cvt2(a0hi.z, a0hi.w);
    av1.u[0] = cvt2(a1lo.x, a1lo.y); av1.u[1] = cvt2(a1lo.z, a1lo.w);
    av1.u[2] = cvt2(a1hi.x, a1hi.y); av1.u[3] = cvt2(a1hi.z, a1hi.w);
    #pragma unroll
    for (int q = 0; q < 4; ++q) {
      bv0.u[q] = cvt2(w0[2 * q], w0[2 * q + 1]);
      bv1.u[q] = cvt2(w1[2 * q], w1[2 * q + 1]);
    }

    // issue next step's loads; they stay in flight across the raw barrier
    if (it + 1 < NSTEP) ISSUE_LOADS((it + 1) * K_STEP);

    const int buf = it & 1;
    xa[buf][tid]       = av0.s;
    xa[buf][tid + 256] = av1.s;
    wb[buf][tid]       = bv0.s;
    wb[buf][tid + 256] = bv1.s;
    barrier_lgkm();   // ds-writes visible; vmcnt NOT drained

    short8 af[4], bf[4];
    #pragma unroll
    for (int m = 0; m < 4; ++m) af[m] = xa[buf][abase + m * 64 + lane];
    #pragma unroll
    for (int n = 0; n < 4; ++n) bf[n] = wb[buf][bbase + n * 64 + lane];
    #pragma unroll
    for (int m = 0; m < 4; ++m)
      #pragma unroll
      for (int n = 0; n < 4; ++n)
        acc[m][n] = __builtin_amdgcn_mfma_f32_16x16x32_bf16(af[m], bf[n], acc[m][n], 0, 0, 0);
  }
#undef ISSUE_LOADS

  // epilogue: C/D layout col = lane&15, row = (lane>>4)*4 + r
  const int lr = lane & 15;
  const int lq = (lane >> 4) * 4;
  float bcol[4];
  #pragma unroll
  for (int n = 0; n < 4; ++n)
    bcol[n] = bias[e * OUT_DIM + c0 + wn + n * 16 + lr];

  #pragma unroll
  for (int m = 0; m < 4; ++m) {
    #pragma unroll
    for (int r = 0; r < 4; ++r) {
      const int gidx = row0 + wm + m * 16 + lq + r;
      if (gidx >= cnt) continue;
      const int grow = rl[gidx];
      float* orow = out + (size_t)grow * OUT_DIM;
      #pragma unroll
      for (int n = 0; n < 4; ++n) {
        const int col = c0 + wn + n * 16 + lr;
        orow[col] = acc[m][n][r] + bcol[n];
      }
    }
  }
}

extern "C" void kernel_launch(void* const* d_in, const int* in_sizes, int n_in,
                              void* d_out, int out_size, void* d_ws, size_t ws_size,
                              hipStream_t stream) {
  (void)in_sizes; (void)n_in; (void)out_size;
  const float* x  = (const float*)d_in[0];
  const float* t  = (const float*)d_in[1];
  const float* W  = (const float*)d_in[2];
  const float* bb = (const float*)d_in[3];
  const float* Wg = (const float*)d_in[4];
  const float* bg = (const float*)d_in[5];
  float* out = (float*)d_out;

  int*   counts  = (int*)d_ws;                                  // 16 ints
  int*   rowlist = (int*)d_ws + 16;                             // 12*2048 ints
  float* wgt     = (float*)((char*)d_ws + 64 + NE * B_ROWS * 4);// 12*4096 f32
  const size_t need = 64 + (size_t)NE * B_ROWS * 4 + (size_t)NE * OUT_DIM * 4;

  hipMemsetAsync(counts, 0, 16 * sizeof(int), stream);
  if (ws_size >= need) {
    wg_transpose<<<OUT_DIM / 256, 256, 0, stream>>>(Wg, wgt);
    gate_kernel<<<B_ROWS, 256, 0, stream>>>(t, wgt, bg, counts, rowlist);
  } else {
    gate_fallback<<<B_ROWS, 256, 0, stream>>>(t, Wg, bg, counts, rowlist);
  }

  dim3 grid(OUT_DIM / N_TILE, (B_ROWS + M_TILE - 1) / M_TILE, NE);
  expert_gemm<<<grid, 256, 0, stream>>>(x, W, bb, counts, rowlist, out);
}